// Round 17
// baseline (16369.504 us; speedup 1.0000x reference)
//
#include <hip/hip_runtime.h>
#include <hip/hip_bf16.h>
#include <hip/hip_cooperative_groups.h>
#include <cstdint>
#include <cstddef>

namespace cg = cooperative_groups;

#define DEVI __device__ __forceinline__

typedef __attribute__((ext_vector_type(8))) short bf16x8;
typedef __attribute__((ext_vector_type(4))) float f32x4;
typedef unsigned short u16;
typedef unsigned int u32;
typedef unsigned long long u64;

DEVI u16 f2bf(float f) {
    u32 i = __builtin_bit_cast(u32, f);
    u32 r = (i + 0x7FFFu + ((i >> 16) & 1u)) >> 16;
    return (u16)r;
}
DEVI float sigmoidf_(float x) { return 1.0f / (1.0f + __expf(-x)); }
DEVI float tanhf_(float x) { return 2.0f / (1.0f + __expf(-2.0f * x)) - 1.0f; }
DEVI float reluf_(float x) { return x > 0.f ? x : 0.f; }

typedef const __attribute__((address_space(1))) void* gptr_t;
typedef __attribute__((address_space(3))) void* lptr_t;

DEVI void gload16(const void* g, void* l) {
    __builtin_amdgcn_global_load_lds((gptr_t)g, (lptr_t)l, 16, 0, 0);
}

// device-scope (sc1 only: coherent at IC/L2-complex, NOT system/DRAM) 16B
// load/store — the only channels used for cross-workgroup h exchange.
DEVI f32x4 gld_sc1(const void* p) {
    f32x4 r;
    asm volatile("global_load_dwordx4 %0, %1, off sc1" : "=v"(r) : "v"(p));
    return r;
}
DEVI void gst_sc1(void* p, f32x4 v) {
    asm volatile("global_store_dwordx4 %0, %1, off sc1" ::"v"(p), "v"(v));
}

__global__ void fill_const(float* __restrict__ p, int n, float v) {
    int i = blockIdx.x * 256 + threadIdx.x;
    if (i < n) p[i] = v;
}

// ---------------- fused setup: all f32->bf16 conversions in ONE launch -----
__global__ void prep_all(const float* __restrict__ x, const float* __restrict__ We1,
                         const float* __restrict__ We2, const float* __restrict__ We3,
                         const float* __restrict__ We41, const float* __restrict__ Wih,
                         const float* __restrict__ Whh, const float* __restrict__ Wf1,
                         const float* __restrict__ Wf2, u16* __restrict__ xb,
                         u16* __restrict__ We1b, u16* __restrict__ We2b,
                         u16* __restrict__ We3b, u16* __restrict__ We41b,
                         u16* __restrict__ WB, u16* __restrict__ Wf1p,
                         u16* __restrict__ Wf2p) {
    const long long T0 = 9961472, T1 = 19922944, T2 = 22020096, T3 = 22544384,
                    T4 = 22806528, T5 = 23592960, T6 = 24379392, T7 = 24403968,
                    T8 = 24436736;
    for (long long i = (long long)blockIdx.x * 256 + threadIdx.x; i < T8;
         i += (long long)gridDim.x * 256) {
        if (i < T1) {
            long long j = (i < T0) ? i : i - T0;
            int r = (int)(j / 4864);
            int c = (int)(j - (long long)r * 4864);
            const float* s = (i < T0) ? x : We1;
            u16* d = (i < T0) ? xb : We1b;
            d[j] = (c < 4860) ? f2bf(s[(size_t)r * 4860 + c]) : (u16)0;
        } else if (i < T2) {
            int j = (int)(i - T1);
            We2b[j] = f2bf(We2[j]);
        } else if (i < T3) {
            int j = (int)(i - T2);
            We3b[j] = f2bf(We3[j]);
        } else if (i < T4) {
            int j = (int)(i - T3);
            We41b[j] = f2bf(We41[j]);
        } else if (i < T5) {
            int j = (int)(i - T4);
            int g = j >> 9, k = j & 511;
            WB[(size_t)g * 1024 + k] = f2bf(Wih[j]);
        } else if (i < T6) {
            int j = (int)(i - T5);
            int g = j >> 9, k = j & 511;
            WB[(size_t)g * 1024 + 512 + k] = f2bf(Whh[j]);
        } else if (i < T7) {
            int j = (int)(i - T6);
            int r = j >> 9;
            Wf1p[j] = (r < 42) ? f2bf(Wf1[j]) : (u16)0;
        } else {
            int j = (int)(i - T7);
            int c = j >> 6, k = j & 63;
            Wf2p[j] = (k < 42) ? f2bf(Wf2[(size_t)c * 42 + k]) : (u16)0;
        }
    }
}

// ---------------- encoder GEMM: C = epi(A @ B^T + bias) (validated) --------
template <int EPI>
__global__ __launch_bounds__(256) void gemm_bt(
    const u16* __restrict__ A, int lda, const u16* __restrict__ B, int ldb,
    const float* __restrict__ bias, u16* __restrict__ C, int ldc, int ktiles,
    const float* __restrict__ eps) {
    __shared__ u16 As[128 * 64];
    __shared__ u16 Bs[128 * 64];
    const int tid = threadIdx.x;
    const int lane = tid & 63;
    const int wave = tid >> 6;
    const int m0 = blockIdx.y * 128;
    const int n0 = blockIdx.x * 128;
    const int l15 = lane & 15, lg = lane >> 4;
    const int wm = (wave >> 1) * 64, wn = (wave & 1) * 64;

    f32x4 acc[4][4];
#pragma unroll
    for (int r = 0; r < 4; r++)
#pragma unroll
        for (int c = 0; c < 4; c++) acc[r][c] = (f32x4){0.f, 0.f, 0.f, 0.f};

    for (int t = 0; t < ktiles; ++t) {
        const int k0 = t * 64;
#pragma unroll
        for (int q = 0; q < 4; ++q) {
            int chunk = q * 4 + wave;
            int o = chunk * 1024 + lane * 16;
            int row = o >> 7;
            int cb = o & 127;
            gload16((const char*)(A + (size_t)(m0 + row) * lda + k0) + cb,
                    (char*)As + chunk * 1024);
            gload16((const char*)(B + (size_t)(n0 + row) * ldb + k0) + cb,
                    (char*)Bs + chunk * 1024);
        }
        __syncthreads();
#pragma unroll
        for (int kf = 0; kf < 2; ++kf) {
            bf16x8 a[4], b[4];
#pragma unroll
            for (int r = 0; r < 4; r++)
                a[r] = *(const bf16x8*)&As[(wm + 16 * r + l15) * 64 + kf * 32 + lg * 8];
#pragma unroll
            for (int c = 0; c < 4; c++)
                b[c] = *(const bf16x8*)&Bs[(wn + 16 * c + l15) * 64 + kf * 32 + lg * 8];
#pragma unroll
            for (int r = 0; r < 4; r++)
#pragma unroll
                for (int c = 0; c < 4; c++)
                    acc[r][c] = __builtin_amdgcn_mfma_f32_16x16x32_bf16(
                        a[r], b[c], acc[r][c], 0, 0, 0);
        }
        __syncthreads();
    }
#pragma unroll
    for (int r = 0; r < 4; r++) {
#pragma unroll
        for (int c = 0; c < 4; c++) {
            int col = n0 + wn + 16 * c + l15;
            float bv = bias[col];
#pragma unroll
            for (int i = 0; i < 4; i++) {
                int row = m0 + wm + 16 * r + lg * 4 + i;
                float v = acc[r][c][i] + bv;
                if (EPI == 0) {
                    v = v > 0.f ? v : 0.f;
                    C[(size_t)row * ldc + col] = f2bf(v);
                } else {
                    float e = eps[(size_t)row * 512 + col];
                    float enc = e * __expf(0.5f * v) + v;
                    C[(size_t)row * ldc + col] = f2bf(enc);
                }
            }
        }
    }
}

// ================= PERSISTENT COOPERATIVE DECODER v3 =======================
// Grid 256 x 1024, 1 block/CU. Partition = R15: sb=bid&7 (64 units),
// rb=bid>>3 (64 rows). ONE grid.sync/step. Coherence: h (bf16) is the only
// cross-WG data, exchanged via sc1 (device-scope, IC-coherent) 16B ops;
// hreg (f32 hold) stays in registers; xt is block-local LDS.
// Fixes vs R16: sc1-only (not system-scope sc0sc1); hT staged ONCE per step
// into LDS; gates use R15's conflict-free BK=64 128B-row swizzled Bst with
// T14 register staging (single buffer); h stores packed -> coalesced 16B.
__global__ __launch_bounds__(1024, 1) void gru_persist(
    const u16* __restrict__ encb, u16* __restrict__ hb0, u16* __restrict__ hb1,
    const u16* __restrict__ WB, const float* __restrict__ bih,
    const float* __restrict__ bhh, const u16* __restrict__ Wf1p,
    const float* __restrict__ bf1, const u16* __restrict__ Wf2p,
    const float* __restrict__ bf2, float* __restrict__ outp) {
    __shared__ __align__(16) u16 xtL[64 * 512];   // 64KB xt tile (swz)
    __shared__ __align__(16) u16 hT[64 * 512];    // 64KB h tile (swz)
    __shared__ __align__(16) u16 Bst[192 * 64];   // 24KB gate-W (BK=64, swz)
    u16* oL = Bst;           // 8KB fc1-out tile (overlay; disjoint lifetime)
    u16* hOut = Bst;         // 8KB h-pack tile (overlay; disjoint lifetime)
    cg::grid_group grid = cg::this_grid();
    const int tid = threadIdx.x, lane = tid & 63, wave = tid >> 6;
    const int wr = wave >> 2, wu = wave & 3;
    const int l15 = lane & 15, lg = lane >> 4;
    const int bid = blockIdx.x;
    const int sb = bid & 7, rb = bid >> 3;
    const int S = sb * 64, m0 = rb * 64;
    const int sw = (l15 & 7) << 4;

    // ---- init: stage xt0=encoded into xtL (swz); zero hT ----
#pragma unroll
    for (int k2 = 0; k2 < 4; ++k2) {
        int j = tid + k2 * 1024;
        int row = j >> 6, slot = j & 63;
        gload16((const char*)(encb + (size_t)(m0 + row) * 512) + (slot ^ (row & 7)) * 16,
                (char*)xtL + j * 16);
    }
    {
        u64* hz = (u64*)hT;
#pragma unroll
        for (int k2 = 0; k2 < 8; ++k2) hz[tid + k2 * 1024] = 0ull;
    }
    f32x4 hreg = (f32x4){0.f, 0.f, 0.f, 0.f};
    const int hu = S + 16 * wu + l15;
    const float br_ = bih[hu] + bhh[hu];
    const float bz_ = bih[512 + hu] + bhh[512 + hu];
    const float bgi = bih[1024 + hu];
    const float bgh = bhh[1024 + hu];
    const int arow = 16 * wr + l15;

    for (int it = 0; it <= 128; ++it) {
        if (it > 0) {
            // ---- hT <- hb[read] rows m0..m0+64 (sc1 coalesced -> LDS) ----
            const u16* hbR = (it & 1) ? hb1 : hb0;
            f32x4 v[4];
#pragma unroll
            for (int k2 = 0; k2 < 4; ++k2) {
                int j = tid + k2 * 1024;
                int row = j >> 6, slot = j & 63;
                v[k2] = gld_sc1((const char*)(hbR + (size_t)(m0 + row) * 512) +
                                (slot ^ (row & 7)) * 16);
            }
            asm volatile("s_waitcnt vmcnt(0)" ::: "memory");
            __builtin_amdgcn_sched_barrier(0);
#pragma unroll
            for (int k2 = 0; k2 < 4; ++k2) {
                int j = tid + k2 * 1024;
                *(f32x4*)((char*)hT + j * 16) = v[k2];
            }
            __syncthreads();  // hT ready (also: prev-step Bst reads done)

            // ---- fc1(h_it) -> out[it-1] (+ oL), waves wu<3 ----
            if (wu < 3) {
                f32x4 oa = (f32x4){0.f, 0.f, 0.f, 0.f};
                const u16* wb1 = Wf1p + (size_t)(16 * wu + l15) * 512 + lg * 8;
#pragma unroll
                for (int kf = 0; kf < 16; ++kf) {
                    bf16x8 a = *(const bf16x8*)((char*)hT + arow * 1024 +
                                                ((kf * 64 + lg * 16) ^ sw));
                    oa = __builtin_amdgcn_mfma_f32_16x16x32_bf16(
                        a, *(const bf16x8*)(wb1 + kf * 32), oa, 0, 0, 0);
                }
                int col = 16 * wu + l15;
                float bv = (col < 42) ? bf1[col] : 0.f;
#pragma unroll
                for (int i = 0; i < 4; ++i) {
                    int row = 16 * wr + lg * 4 + i;
                    float v2 = reluf_(oa[i] + bv);
                    if (col >= 42) v2 = 0.f;
                    int cb = col * 2;
                    *(u16*)((char*)oL + row * 128 +
                            (((cb & ~15) ^ ((row & 7) << 4)) | (cb & 15))) = f2bf(v2);
                    if (sb == 0 && col < 42)
                        outp[(size_t)(m0 + row) * 5376 + (size_t)(it - 1) * 42 + col] = v2;
                }
            }
            if (it == 128) break;
            __syncthreads();  // oL ready

            // ---- fc2(oL) -> xtL ----
            bf16x8 a2[2];
#pragma unroll
            for (int kf = 0; kf < 2; ++kf) {
                int row = 16 * wr + l15;
                a2[kf] = *(const bf16x8*)((char*)oL + row * 128 +
                                          ((kf * 64 + lg * 16) ^ ((row & 7) << 4)));
            }
#pragma unroll
            for (int ci = 0; ci < 8; ++ci) {
                int col = 128 * wu + 16 * ci + l15;
                const u16* wb2 = Wf2p + (size_t)col * 64 + lg * 8;
                f32x4 xa = (f32x4){0.f, 0.f, 0.f, 0.f};
                xa = __builtin_amdgcn_mfma_f32_16x16x32_bf16(a2[0], *(const bf16x8*)wb2, xa, 0, 0, 0);
                xa = __builtin_amdgcn_mfma_f32_16x16x32_bf16(a2[1], *(const bf16x8*)(wb2 + 32), xa, 0, 0, 0);
                float bv = bf2[col];
                int cb = col * 2;
#pragma unroll
                for (int i = 0; i < 4; ++i) {
                    int row = 16 * wr + lg * 4 + i;
                    float v2 = reluf_(xa[i] + bv);
                    *(u16*)((char*)xtL + row * 1024 +
                            (((cb & ~15) ^ ((row & 7) << 4)) | (cb & 15))) = f2bf(v2);
                }
            }
        }
        __syncthreads();  // xtL ready; oL dead (safe to write Bst)

        // ---- gates: K=1024 = xt(t<8)||h(t>=8); BK=64, T14 reg-staged ----
        // chunk j: row=j>>3 (0..191), slot=j&7; src pre-swizzled, LDS linear.
        auto srcB = [&](int j, int t) -> const u16* {
            int row = j >> 3, slot = j & 7;
            int gate = row >> 6, unit = row & 63;
            return WB + (size_t)(gate * 512 + S + unit) * 1024 + t * 64 +
                   (slot ^ (row & 7)) * 8;
        };
        f32x4 ar = (f32x4){0.f, 0.f, 0.f, 0.f};
        f32x4 az = ar, agi = ar, agh = ar;
        bf16x8 s0, s1;
        // prologue: stage t=0 directly
        s0 = *(const bf16x8*)srcB(tid, 0);
        if (tid < 512) s1 = *(const bf16x8*)srcB(tid + 1024, 0);
        *(bf16x8*)((char*)Bst + tid * 16) = s0;
        if (tid < 512) *(bf16x8*)((char*)Bst + (tid + 1024) * 16) = s1;
        __syncthreads();
        for (int t = 0; t < 16; ++t) {
            if (t < 15) {  // issue loads for t+1 (land during compute)
                s0 = *(const bf16x8*)srcB(tid, t + 1);
                if (tid < 512) s1 = *(const bf16x8*)srcB(tid + 1024, t + 1);
            }
            __builtin_amdgcn_sched_barrier(0);
            bf16x8 a[2];
#pragma unroll
            for (int kf = 0; kf < 2; ++kf) {
                int kb = (t < 8 ? t : t - 8) * 128 + kf * 64 + lg * 16;
                const char* base = (t < 8) ? (const char*)xtL : (const char*)hT;
                a[kf] = *(const bf16x8*)(base + arow * 1024 + (kb ^ sw));
            }
            int rb0 = 16 * wu + l15;
            int swb = (rb0 & 7) << 4;
#pragma unroll
            for (int kf = 0; kf < 2; ++kf) {
                int kb = kf * 64 + lg * 16;
                bf16x8 br = *(const bf16x8*)((char*)Bst + (size_t)rb0 * 128 + (kb ^ swb));
                bf16x8 bz = *(const bf16x8*)((char*)Bst + (size_t)(64 + rb0) * 128 + (kb ^ swb));
                bf16x8 bn = *(const bf16x8*)((char*)Bst + (size_t)(128 + rb0) * 128 + (kb ^ swb));
                ar = __builtin_amdgcn_mfma_f32_16x16x32_bf16(a[kf], br, ar, 0, 0, 0);
                az = __builtin_amdgcn_mfma_f32_16x16x32_bf16(a[kf], bz, az, 0, 0, 0);
                if (t < 8)
                    agi = __builtin_amdgcn_mfma_f32_16x16x32_bf16(a[kf], bn, agi, 0, 0, 0);
                else
                    agh = __builtin_amdgcn_mfma_f32_16x16x32_bf16(a[kf], bn, agh, 0, 0, 0);
            }
            __syncthreads();  // all Bst(t) reads done
            if (t < 15) {
                *(bf16x8*)((char*)Bst + tid * 16) = s0;  // compiler waits vmcnt
                if (tid < 512) *(bf16x8*)((char*)Bst + (tid + 1024) * 16) = s1;
                __syncthreads();  // Bst(t+1) visible
            }
        }

        // ---- GRU update: hreg + packed coalesced sc1 h store ----
        __syncthreads();  // Bst dead -> hOut overlay safe
#pragma unroll
        for (int i = 0; i < 4; ++i) {
            int row = 16 * wr + lg * 4 + i;
            float rv = sigmoidf_(ar[i] + br_);
            float zv = sigmoidf_(az[i] + bz_);
            float nv = tanhf_(agi[i] + bgi + rv * (agh[i] + bgh));
            float hn = (1.f - zv) * nv + zv * hreg[i];
            hreg[i] = hn;
            *(u16*)((char*)hOut + row * 128 + (16 * wu + l15) * 2) = f2bf(hn);
        }
        __syncthreads();  // hOut complete
        u16* hbW = (it & 1) ? hb0 : hb1;
        if (tid < 512) {
            int row = tid >> 3, part = tid & 7;
            f32x4 hv = *(const f32x4*)((char*)hOut + row * 128 + part * 16);
            gst_sc1((char*)(hbW + (size_t)(m0 + row) * 512 + S) + part * 16, hv);
        }
        asm volatile("s_waitcnt vmcnt(0)" ::: "memory");
        __threadfence();
        grid.sync();
    }
}

// ================= FALLBACK per-step kernel (R15-validated) ================
template <int MODE>
__global__ __launch_bounds__(1024, 1) void gru_step(
    const u16* __restrict__ xt0, const u16* __restrict__ hbR,
    const float* __restrict__ hfR, u16* __restrict__ hbW,
    float* __restrict__ hfW, const u16* __restrict__ WB,
    const float* __restrict__ bih, const float* __restrict__ bhh,
    const u16* __restrict__ Wf1p, const float* __restrict__ bf1,
    const u16* __restrict__ Wf2p, const float* __restrict__ bf2,
    float* __restrict__ outp, int sidx) {
    __shared__ __align__(16) u16 xtL[64 * 512];
    __shared__ __align__(16) u16 Bst[2][192 * 64];
    __shared__ __align__(16) u16 oL[64 * 64];
    const int tid = threadIdx.x, lane = tid & 63, wave = tid >> 6;
    const int wr = wave >> 2, wu = wave & 3;
    const int l15 = lane & 15, lg = lane >> 4;
    const int bid = blockIdx.x;
    const int sb = (MODE == 2) ? 0 : (bid & 7);
    const int rb = (MODE == 2) ? bid : (bid >> 3);
    const int S = sb * 64, m0 = rb * 64;
    const int sw = (l15 & 7) << 4;

    if (MODE == 0) {
#pragma unroll
        for (int k2 = 0; k2 < 4; ++k2) {
            int j = tid + k2 * 1024;
            int row = j >> 6, slot = j & 63;
            gload16((const char*)(xt0 + (size_t)(m0 + row) * 512) + (slot ^ (row & 7)) * 16,
                    (char*)xtL + j * 16);
        }
    }
    if (MODE >= 1) {
        if (MODE == 1) {
            ((u64*)oL)[tid] = 0ull;
            __syncthreads();
        }
        if (wu < 3) {
            f32x4 oa = (f32x4){0.f, 0.f, 0.f, 0.f};
            const u16* ha = hbR + (size_t)(m0 + 16 * wr + l15) * 512 + lg * 8;
            const u16* wb1 = Wf1p + (size_t)(16 * wu + l15) * 512 + lg * 8;
#pragma unroll
            for (int kf = 0; kf < 16; ++kf) {
                bf16x8 a = *(const bf16x8*)(ha + kf * 32);
                bf16x8 b = *(const bf16x8*)(wb1 + kf * 32);
                oa = __builtin_amdgcn_mfma_f32_16x16x32_bf16(a, b, oa, 0, 0, 0);
            }
            int col = 16 * wu + l15;
            float bv = (col < 42) ? bf1[col] : 0.f;
#pragma unroll
            for (int i = 0; i < 4; ++i) {
                int row = 16 * wr + lg * 4 + i;
                float v = reluf_(oa[i] + bv);
                if (col >= 42) v = 0.f;
                if (MODE == 1) {
                    int cb = col * 2;
                    *(u16*)((char*)oL + row * 128 +
                            (((cb & ~15) ^ ((row & 7) << 4)) | (cb & 15))) = f2bf(v);
                }
                if (sb == 0 && col < 42)
                    outp[(size_t)(m0 + row) * 5376 + (size_t)sidx * 42 + col] = v;
            }
        }
    }
    if (MODE == 1) {
        __syncthreads();
        bf16x8 a2[2];
#pragma unroll
        for (int kf = 0; kf < 2; ++kf) {
            int row = 16 * wr + l15;
            a2[kf] = *(const bf16x8*)((char*)oL + row * 128 +
                                      ((kf * 64 + lg * 16) ^ ((row & 7) << 4)));
        }
#pragma unroll
        for (int ci = 0; ci < 8; ++ci) {
            int col = 128 * wu + 16 * ci + l15;
            const u16* wb2 = Wf2p + (size_t)col * 64 + lg * 8;
            f32x4 xa = (f32x4){0.f, 0.f, 0.f, 0.f};
            xa = __builtin_amdgcn_mfma_f32_16x16x32_bf16(a2[0], *(const bf16x8*)wb2, xa, 0, 0, 0);
            xa = __builtin_amdgcn_mfma_f32_16x16x32_bf16(a2[1], *(const bf16x8*)(wb2 + 32), xa, 0, 0, 0);
            float bv = bf2[col];
            int cb = col * 2;
#pragma unroll
            for (int i = 0; i < 4; ++i) {
                int row = 16 * wr + lg * 4 + i;
                float v = reluf_(xa[i] + bv);
                *(u16*)((char*)xtL + row * 1024 +
                        (((cb & ~15) ^ ((row & 7) << 4)) | (cb & 15))) = f2bf(v);
            }
        }
    }
    if (MODE <= 1) {
        __syncthreads();
        auto stageB = [&](int buf, int t) {
            {
                int j = tid;
                int row = j >> 3, slot = j & 7;
                int gate = row >> 6, unit = row & 63;
                gload16(WB + (size_t)(gate * 512 + S + unit) * 1024 + t * 64 +
                            (slot ^ (row & 7)) * 8,
                        (char*)Bst + buf * 24576 + j * 16);
            }
            if (tid < 512) {
                int j = tid + 1024;
                int row = j >> 3, slot = j & 7;
                int gate = row >> 6, unit = row & 63;
                gload16(WB + (size_t)(gate * 512 + S + unit) * 1024 + t * 64 +
                            (slot ^ (row & 7)) * 8,
                        (char*)Bst + buf * 24576 + j * 16);
            }
        };
        f32x4 ar = (f32x4){0.f, 0.f, 0.f, 0.f};
        f32x4 az = ar, agi = ar, agh = ar;
        const int arow = 16 * wr + l15;
        const u16* hrow = hbR + (size_t)(m0 + arow) * 512 + lg * 8;
        bf16x8 hc0, hc1, hp0, hp1;
        stageB(0, 0);
        for (int t = 0; t < 16; ++t) {
            if (t >= 7 && t < 15) {
                const u16* hs = hrow + (t - 7) * 64;
                hp0 = *(const bf16x8*)hs;
                hp1 = *(const bf16x8*)(hs + 32);
            }
            if (t < 15) stageB((t + 1) & 1, t + 1);
            __builtin_amdgcn_sched_barrier(0);
            if (t == 15) {
                asm volatile("s_waitcnt vmcnt(0)");
            } else if (t >= 7) {
                if (wave < 8) asm volatile("s_waitcnt vmcnt(4)");
                else          asm volatile("s_waitcnt vmcnt(3)");
            } else {
                if (wave < 8) asm volatile("s_waitcnt vmcnt(2)");
                else          asm volatile("s_waitcnt vmcnt(1)");
            }
            __builtin_amdgcn_sched_barrier(0);
            __builtin_amdgcn_s_barrier();
            __builtin_amdgcn_sched_barrier(0);
            bf16x8 a[2];
            if (t < 8) {
#pragma unroll
                for (int kf = 0; kf < 2; ++kf)
                    a[kf] = *(const bf16x8*)((char*)xtL + arow * 1024 +
                                             ((t * 128 + kf * 64 + lg * 16) ^ sw));
            } else {
                a[0] = hc0;
                a[1] = hc1;
            }
            const char* bb = (const char*)Bst + (t & 1) * 24576;
            int rb0 = 16 * wu + l15;
            int swb = (rb0 & 7) << 4;
#pragma unroll
            for (int kf = 0; kf < 2; ++kf) {
                int kb = kf * 64 + lg * 16;
                bf16x8 br = *(const bf16x8*)(bb + (size_t)rb0 * 128 + (kb ^ swb));
                bf16x8 bz = *(const bf16x8*)(bb + (size_t)(64 + rb0) * 128 + (kb ^ swb));
                bf16x8 bn = *(const bf16x8*)(bb + (size_t)(128 + rb0) * 128 + (kb ^ swb));
                ar = __builtin_amdgcn_mfma_f32_16x16x32_bf16(a[kf], br, ar, 0, 0, 0);
                az = __builtin_amdgcn_mfma_f32_16x16x32_bf16(a[kf], bz, az, 0, 0, 0);
                if (t < 8)
                    agi = __builtin_amdgcn_mfma_f32_16x16x32_bf16(a[kf], bn, agi, 0, 0, 0);
                else
                    agh = __builtin_amdgcn_mfma_f32_16x16x32_bf16(a[kf], bn, agh, 0, 0, 0);
            }
            hc0 = hp0;
            hc1 = hp1;
            __builtin_amdgcn_sched_barrier(0);
            __builtin_amdgcn_s_barrier();
        }
        int hu = S + 16 * wu + l15;
        float br_ = bih[hu] + bhh[hu];
        float bz_ = bih[512 + hu] + bhh[512 + hu];
        float bgi = bih[1024 + hu];
        float bgh = bhh[1024 + hu];
#pragma unroll
        for (int i = 0; i < 4; ++i) {
            int row = m0 + 16 * wr + lg * 4 + i;
            float rv = sigmoidf_(ar[i] + br_);
            float zv = sigmoidf_(az[i] + bz_);
            float nv = tanhf_(agi[i] + bgi + rv * (agh[i] + bgh));
            float hold = hfR[(size_t)row * 512 + hu];
            float hn = (1.f - zv) * nv + zv * hold;
            hfW[(size_t)row * 512 + hu] = hn;
            hbW[(size_t)row * 512 + hu] = f2bf(hn);
        }
    }
}

// ---------------------------------------------------------------------------
extern "C" void kernel_launch(void* const* d_in, const int* in_sizes, int n_in,
                              void* d_out, int out_size, void* d_ws,
                              size_t ws_size, hipStream_t stream) {
    (void)in_sizes; (void)n_in; (void)out_size;
    const float* x = (const float*)d_in[0];
    const float* eps = (const float*)d_in[2];
    const float* We1 = (const float*)d_in[3];
    const float* be1 = (const float*)d_in[4];
    const float* We2 = (const float*)d_in[5];
    const float* be2 = (const float*)d_in[6];
    const float* We3 = (const float*)d_in[7];
    const float* be3 = (const float*)d_in[8];
    const float* We41 = (const float*)d_in[9];
    const float* be41 = (const float*)d_in[10];
    const float* Wih = (const float*)d_in[11];
    const float* bih = (const float*)d_in[12];
    const float* Whh = (const float*)d_in[13];
    const float* bhh = (const float*)d_in[14];
    const float* Wf1 = (const float*)d_in[15];
    const float* bf1 = (const float*)d_in[16];
    const float* Wf2 = (const float*)d_in[17];
    const float* bf2 = (const float*)d_in[18];
    float* out = (float*)d_out;

    char* ws = (char*)d_ws;
    size_t off = 0;
    auto alloc = [&](size_t bytes) -> char* {
        char* p = ws + off;
        off += (bytes + 255) & ~(size_t)255;
        return p;
    };
    u16* xb = (u16*)alloc(2048ull * 4864 * 2);
    u16* We1b = (u16*)alloc(2048ull * 4864 * 2);
    u16* We2b = (u16*)alloc(1024ull * 2048 * 2);
    u16* We3b = (u16*)alloc(512ull * 1024 * 2);
    u16* We41b = (u16*)alloc(512ull * 512 * 2);
    u16* WB = (u16*)alloc(1536ull * 1024 * 2);
    u16* h1b = (u16*)alloc(2048ull * 2048 * 2);
    u16* h2b = (u16*)alloc(2048ull * 1024 * 2);
    u16* h3b = (u16*)alloc(2048ull * 512 * 2);
    u16* encb = (u16*)alloc(2048ull * 512 * 2);
    u16* hb0 = (u16*)alloc(2048ull * 512 * 2);
    u16* hb1 = (u16*)alloc(2048ull * 512 * 2);
    float* hf0 = (float*)alloc(2048ull * 512 * 4);
    float* hf1 = (float*)alloc(2048ull * 512 * 4);
    u16* Wf1p = (u16*)alloc(48ull * 512 * 2);
    u16* Wf2p = (u16*)alloc(512ull * 64 * 2);
    if (off > ws_size) {
        fill_const<<<(11010048 + 255) / 256, 256, 0, stream>>>(out, 11010048, 54321.0f);
        return;
    }

    prep_all<<<8192, 256, 0, stream>>>(x, We1, We2, We3, We41, Wih, Whh, Wf1, Wf2,
                                       xb, We1b, We2b, We3b, We41b, WB, Wf1p, Wf2p);

    gemm_bt<0><<<dim3(16, 16), 256, 0, stream>>>(xb, 4864, We1b, 4864, be1, h1b, 2048, 76, nullptr);
    gemm_bt<0><<<dim3(8, 16), 256, 0, stream>>>(h1b, 2048, We2b, 2048, be2, h2b, 1024, 32, nullptr);
    gemm_bt<0><<<dim3(4, 16), 256, 0, stream>>>(h2b, 1024, We3b, 1024, be3, h3b, 512, 16, nullptr);
    gemm_bt<1><<<dim3(4, 16), 256, 0, stream>>>(h3b, 512, We41b, 512, be41, encb, 512, 8, eps);

    // ---- persistent cooperative decoder v3 (1 launch, 6 nodes total) ----
    {
        const u16* encb_a = encb;
        void* kargs[] = {(void*)&encb_a, &hb0, &hb1, &WB, (void*)&bih, (void*)&bhh,
                         &Wf1p, (void*)&bf1, &Wf2p, (void*)&bf2, &out};
        hipError_t e = hipLaunchCooperativeKernel((const void*)gru_persist,
                                                  dim3(256), dim3(1024), kargs, 0, stream);
        if (e == hipSuccess) return;
        (void)hipGetLastError();
    }

    // ---- fallback: R15-validated per-step path ----
    hipMemsetAsync(hb0, 0, 2048ull * 512 * 2, stream);
    hipMemsetAsync(hf0, 0, 2048ull * 512 * 4, stream);
    u16* hb[2] = {hb0, hb1};
    float* hfl[2] = {hf0, hf1};
    gru_step<0><<<256, 1024, 0, stream>>>(encb, hb0, hf0, hb1, hf1, WB, bih,
                                          bhh, Wf1p, bf1, Wf2p, bf2, out, 0);
    for (int i = 1; i < 128; ++i) {
        int p = i & 1;
        gru_step<1><<<256, 1024, 0, stream>>>(nullptr, hb[p], hfl[p],
                                              hb[p ^ 1], hfl[p ^ 1], WB, bih,
                                              bhh, Wf1p, bf1, Wf2p, bf2, out,
                                              i - 1);
    }
    gru_step<2><<<32, 1024, 0, stream>>>(nullptr, hb0, hf0, nullptr, nullptr,
                                         WB, bih, bhh, Wf1p, bf1, Wf2p, bf2,
                                         out, 127);
}

// Round 18
// 4740.141 us; speedup vs baseline: 3.4534x; 3.4534x over previous
//
#include <hip/hip_runtime.h>
#include <hip/hip_bf16.h>
#include <cstdint>
#include <cstddef>

#define DEVI __device__ __forceinline__

typedef __attribute__((ext_vector_type(8))) short bf16x8;
typedef __attribute__((ext_vector_type(4))) float f32x4;
typedef unsigned short u16;
typedef unsigned int u32;
typedef unsigned long long u64;

DEVI u16 f2bf(float f) {
    u32 i = __builtin_bit_cast(u32, f);
    u32 r = (i + 0x7FFFu + ((i >> 16) & 1u)) >> 16;
    return (u16)r;
}
DEVI float sigmoidf_(float x) { return 1.0f / (1.0f + __expf(-x)); }
DEVI float tanhf_(float x) { return 2.0f / (1.0f + __expf(-2.0f * x)) - 1.0f; }
DEVI float reluf_(float x) { return x > 0.f ? x : 0.f; }

typedef const __attribute__((address_space(1))) void* gptr_t;
typedef __attribute__((address_space(3))) void* lptr_t;

DEVI void gload16(const void* g, void* l) {
    __builtin_amdgcn_global_load_lds((gptr_t)g, (lptr_t)l, 16, 0, 0);
}

__global__ void fill_const(float* __restrict__ p, int n, float v) {
    int i = blockIdx.x * 256 + threadIdx.x;
    if (i < n) p[i] = v;
}

// ---------------- fused setup: all f32->bf16 conversions in ONE launch -----
__global__ void prep_all(const float* __restrict__ x, const float* __restrict__ We1,
                         const float* __restrict__ We2, const float* __restrict__ We3,
                         const float* __restrict__ We41, const float* __restrict__ Wih,
                         const float* __restrict__ Whh, const float* __restrict__ Wf1,
                         const float* __restrict__ Wf2, u16* __restrict__ xb,
                         u16* __restrict__ We1b, u16* __restrict__ We2b,
                         u16* __restrict__ We3b, u16* __restrict__ We41b,
                         u16* __restrict__ WB, u16* __restrict__ Wf1p,
                         u16* __restrict__ Wf2p) {
    const long long T0 = 9961472, T1 = 19922944, T2 = 22020096, T3 = 22544384,
                    T4 = 22806528, T5 = 23592960, T6 = 24379392, T7 = 24403968,
                    T8 = 24436736;
    for (long long i = (long long)blockIdx.x * 256 + threadIdx.x; i < T8;
         i += (long long)gridDim.x * 256) {
        if (i < T1) {  // xb / We1b: [2048][4864] zero-padded from [2048][4860]
            long long j = (i < T0) ? i : i - T0;
            int r = (int)(j / 4864);
            int c = (int)(j - (long long)r * 4864);
            const float* s = (i < T0) ? x : We1;
            u16* d = (i < T0) ? xb : We1b;
            d[j] = (c < 4860) ? f2bf(s[(size_t)r * 4860 + c]) : (u16)0;
        } else if (i < T2) {
            int j = (int)(i - T1);
            We2b[j] = f2bf(We2[j]);
        } else if (i < T3) {
            int j = (int)(i - T2);
            We3b[j] = f2bf(We3[j]);
        } else if (i < T4) {
            int j = (int)(i - T3);
            We41b[j] = f2bf(We41[j]);
        } else if (i < T5) {  // WB[g][0:512] = Wih
            int j = (int)(i - T4);
            int g = j >> 9, k = j & 511;
            WB[(size_t)g * 1024 + k] = f2bf(Wih[j]);
        } else if (i < T6) {  // WB[g][512:1024] = Whh
            int j = (int)(i - T5);
            int g = j >> 9, k = j & 511;
            WB[(size_t)g * 1024 + 512 + k] = f2bf(Whh[j]);
        } else if (i < T7) {  // Wf1p [48][512], rows >=42 zero
            int j = (int)(i - T6);
            int r = j >> 9;
            Wf1p[j] = (r < 42) ? f2bf(Wf1[j]) : (u16)0;
        } else {  // Wf2p [512][64], k >= 42 zero
            int j = (int)(i - T7);
            int c = j >> 6, k = j & 63;
            Wf2p[j] = (k < 42) ? f2bf(Wf2[(size_t)c * 42 + k]) : (u16)0;
        }
    }
}

// ---------------- encoder GEMM: C = epi(A @ B^T + bias) (validated) --------
template <int EPI>
__global__ __launch_bounds__(256) void gemm_bt(
    const u16* __restrict__ A, int lda, const u16* __restrict__ B, int ldb,
    const float* __restrict__ bias, u16* __restrict__ C, int ldc, int ktiles,
    const float* __restrict__ eps) {
    __shared__ u16 As[128 * 64];
    __shared__ u16 Bs[128 * 64];
    const int tid = threadIdx.x;
    const int lane = tid & 63;
    const int wave = tid >> 6;
    const int m0 = blockIdx.y * 128;
    const int n0 = blockIdx.x * 128;
    const int l15 = lane & 15, lg = lane >> 4;
    const int wm = (wave >> 1) * 64, wn = (wave & 1) * 64;

    f32x4 acc[4][4];
#pragma unroll
    for (int r = 0; r < 4; r++)
#pragma unroll
        for (int c = 0; c < 4; c++) acc[r][c] = (f32x4){0.f, 0.f, 0.f, 0.f};

    for (int t = 0; t < ktiles; ++t) {
        const int k0 = t * 64;
#pragma unroll
        for (int q = 0; q < 4; ++q) {
            int chunk = q * 4 + wave;
            int o = chunk * 1024 + lane * 16;
            int row = o >> 7;
            int cb = o & 127;
            gload16((const char*)(A + (size_t)(m0 + row) * lda + k0) + cb,
                    (char*)As + chunk * 1024);
            gload16((const char*)(B + (size_t)(n0 + row) * ldb + k0) + cb,
                    (char*)Bs + chunk * 1024);
        }
        __syncthreads();
#pragma unroll
        for (int kf = 0; kf < 2; ++kf) {
            bf16x8 a[4], b[4];
#pragma unroll
            for (int r = 0; r < 4; r++)
                a[r] = *(const bf16x8*)&As[(wm + 16 * r + l15) * 64 + kf * 32 + lg * 8];
#pragma unroll
            for (int c = 0; c < 4; c++)
                b[c] = *(const bf16x8*)&Bs[(wn + 16 * c + l15) * 64 + kf * 32 + lg * 8];
#pragma unroll
            for (int r = 0; r < 4; r++)
#pragma unroll
                for (int c = 0; c < 4; c++)
                    acc[r][c] = __builtin_amdgcn_mfma_f32_16x16x32_bf16(
                        a[r], b[c], acc[r][c], 0, 0, 0);
        }
        __syncthreads();
    }
#pragma unroll
    for (int r = 0; r < 4; r++) {
#pragma unroll
        for (int c = 0; c < 4; c++) {
            int col = n0 + wn + 16 * c + l15;
            float bv = bias[col];
#pragma unroll
            for (int i = 0; i < 4; i++) {
                int row = m0 + wm + 16 * r + lg * 4 + i;
                float v = acc[r][c][i] + bv;
                if (EPI == 0) {
                    v = v > 0.f ? v : 0.f;
                    C[(size_t)row * ldc + col] = f2bf(v);
                } else {
                    float e = eps[(size_t)row * 512 + col];
                    float enc = e * __expf(0.5f * v) + v;
                    C[(size_t)row * ldc + col] = f2bf(enc);
                }
            }
        }
    }
}

// ================= FUSED PER-STEP DECODER (2-deep pipeline) ================
// Linear grid 256; sb = bid&7 (XCD-resident WB slice), rb = bid>>3.
// Block: 64 rows x 64 units; wave (wr,wu): 16 rows x 16 units.
// Gates: Bst 3-buffer, stage(t+2) + h-prefetch(t+2) both 2-deep in flight
// across raw barriers; counted vmcnt waits only for iteration t's data.
// fc1: k-split-4 accumulators (breaks the serial MFMA chain).
template <int MODE>
__global__ __launch_bounds__(1024, 1) void gru_step(
    const u16* __restrict__ xt0, const u16* __restrict__ hbR,
    const float* __restrict__ hfR, u16* __restrict__ hbW,
    float* __restrict__ hfW, const u16* __restrict__ WB,
    const float* __restrict__ bih, const float* __restrict__ bhh,
    const u16* __restrict__ Wf1p, const float* __restrict__ bf1,
    const u16* __restrict__ Wf2p, const float* __restrict__ bf2,
    float* __restrict__ outp, int sidx) {
    __shared__ __align__(16) u16 xtL[64 * 512];     // 64KB swizzled xt tile
    __shared__ __align__(16) u16 Bst[3][192 * 64];  // 3x24KB gate-W bufs
    __shared__ __align__(16) u16 oL[64 * 64];       // 8KB fc1-out tile
    const int tid = threadIdx.x, lane = tid & 63, wave = tid >> 6;
    const int wr = wave >> 2, wu = wave & 3;
    const int l15 = lane & 15, lg = lane >> 4;
    const int bid = blockIdx.x;
    const int sb = (MODE == 2) ? 0 : (bid & 7);
    const int rb = (MODE == 2) ? bid : (bid >> 3);
    const int S = sb * 64, m0 = rb * 64;
    const int sw = (l15 & 7) << 4;

    if (MODE == 0) {
        // stage xtL from encoded: 4096 16B issues, src slot pre-swizzled
#pragma unroll
        for (int k2 = 0; k2 < 4; ++k2) {
            int j = tid + k2 * 1024;
            int row = j >> 6, slot = j & 63;
            gload16((const char*)(xt0 + (size_t)(m0 + row) * 512) + (slot ^ (row & 7)) * 16,
                    (char*)xtL + j * 16);
        }
    }

    if (MODE >= 1) {
        if (MODE == 1) {
            ((u64*)oL)[tid] = 0ull;  // zero incl. pad cols 48..63
            __syncthreads();
        }
        // ---- fc1: 16 rows x 16 cols per wave (wu<3), k-split-4 acc ----
        if (wu < 3) {
            f32x4 oa0 = (f32x4){0.f, 0.f, 0.f, 0.f};
            f32x4 oa1 = oa0, oa2 = oa0, oa3 = oa0;
            const u16* ha = hbR + (size_t)(m0 + 16 * wr + l15) * 512 + lg * 8;
            const u16* wb1 = Wf1p + (size_t)(16 * wu + l15) * 512 + lg * 8;
#pragma unroll
            for (int kf = 0; kf < 4; ++kf) {
                oa0 = __builtin_amdgcn_mfma_f32_16x16x32_bf16(
                    *(const bf16x8*)(ha + kf * 32), *(const bf16x8*)(wb1 + kf * 32), oa0, 0, 0, 0);
                oa1 = __builtin_amdgcn_mfma_f32_16x16x32_bf16(
                    *(const bf16x8*)(ha + (kf + 4) * 32), *(const bf16x8*)(wb1 + (kf + 4) * 32), oa1, 0, 0, 0);
                oa2 = __builtin_amdgcn_mfma_f32_16x16x32_bf16(
                    *(const bf16x8*)(ha + (kf + 8) * 32), *(const bf16x8*)(wb1 + (kf + 8) * 32), oa2, 0, 0, 0);
                oa3 = __builtin_amdgcn_mfma_f32_16x16x32_bf16(
                    *(const bf16x8*)(ha + (kf + 12) * 32), *(const bf16x8*)(wb1 + (kf + 12) * 32), oa3, 0, 0, 0);
            }
            f32x4 oa = (oa0 + oa1) + (oa2 + oa3);
            int col = 16 * wu + l15;
            float bv = (col < 42) ? bf1[col] : 0.f;
#pragma unroll
            for (int i = 0; i < 4; ++i) {
                int row = 16 * wr + lg * 4 + i;
                float v = reluf_(oa[i] + bv);
                if (col >= 42) v = 0.f;
                if (MODE == 1) {
                    int cb = col * 2;
                    *(u16*)((char*)oL + row * 128 +
                            (((cb & ~15) ^ ((row & 7) << 4)) | (cb & 15))) = f2bf(v);
                }
                if (sb == 0 && col < 42)
                    outp[(size_t)(m0 + row) * 5376 + (size_t)sidx * 42 + col] = v;
            }
        }
    }

    if (MODE == 1) {
        __syncthreads();  // oL complete
        // ---- fc2: 16 rows x 128 cols per wave -> xtL ----
        bf16x8 a2[2];
#pragma unroll
        for (int kf = 0; kf < 2; ++kf) {
            int row = 16 * wr + l15;
            a2[kf] = *(const bf16x8*)((char*)oL + row * 128 +
                                      ((kf * 64 + lg * 16) ^ ((row & 7) << 4)));
        }
#pragma unroll
        for (int ci = 0; ci < 8; ++ci) {
            int col = 128 * wu + 16 * ci + l15;
            const u16* wb2 = Wf2p + (size_t)col * 64 + lg * 8;
            f32x4 xa = (f32x4){0.f, 0.f, 0.f, 0.f};
            xa = __builtin_amdgcn_mfma_f32_16x16x32_bf16(a2[0], *(const bf16x8*)wb2, xa, 0, 0, 0);
            xa = __builtin_amdgcn_mfma_f32_16x16x32_bf16(a2[1], *(const bf16x8*)(wb2 + 32), xa, 0, 0, 0);
            float bv = bf2[col];
            int cb = col * 2;
#pragma unroll
            for (int i = 0; i < 4; ++i) {
                int row = 16 * wr + lg * 4 + i;
                float v = reluf_(xa[i] + bv);
                *(u16*)((char*)xtL + row * 1024 +
                        (((cb & ~15) ^ ((row & 7) << 4)) | (cb & 15))) = f2bf(v);
            }
        }
    }

    if (MODE <= 1) {
        __syncthreads();  // xtL ready (MODE0 stage drain or fc2 ds_writes)

        // ---- gates: r,z over [xt||h]; gi_n (t<8), gh_n (t>=8) ----
        auto stageB = [&](int buf, int t) {
            {
                int j = tid;
                int row = j >> 3, slot = j & 7;
                int gate = row >> 6, unit = row & 63;
                gload16(WB + (size_t)(gate * 512 + S + unit) * 1024 + t * 64 +
                            (slot ^ (row & 7)) * 8,
                        (char*)Bst + buf * 24576 + j * 16);
            }
            if (tid < 512) {  // waves 0-7 only (wave-uniform)
                int j = tid + 1024;
                int row = j >> 3, slot = j & 7;
                int gate = row >> 6, unit = row & 63;
                gload16(WB + (size_t)(gate * 512 + S + unit) * 1024 + t * 64 +
                            (slot ^ (row & 7)) * 8,
                        (char*)Bst + buf * 24576 + j * 16);
            }
        };
        f32x4 ar = (f32x4){0.f, 0.f, 0.f, 0.f};
        f32x4 az = ar, agi = ar, agh = ar;
        const int arow = 16 * wr + l15;
        const u16* hrow = hbR + (size_t)(m0 + arow) * 512 + lg * 8;
        bf16x8 hc0, hc1, hp1a, hp1b, hp2a, hp2b;

        // prologue: 2 stages in flight
        stageB(0, 0);
        stageB(1, 1);
        for (int t = 0; t < 16; ++t) {
            // issue h-prefetch for t+2 (2 loads/wave, h-range t+2 in [8,15])
            if (t >= 6 && t < 14) {
                const u16* hs = hrow + (t - 6) * 64;
                hp2a = *(const bf16x8*)hs;
                hp2b = *(const bf16x8*)(hs + 32);
            }
            // issue B-stage for t+2
            if (t < 14) stageB((t + 2) % 3, t + 2);
            __builtin_amdgcn_sched_barrier(0);
            // counted wait: stage(t) (+hpf(t) if t>=8) done; everything for
            // t+1 and t+2 stays in flight across the barrier.
            if (t < 6) {
                if (wave < 8) asm volatile("s_waitcnt vmcnt(4)");
                else          asm volatile("s_waitcnt vmcnt(2)");
            } else if (t == 6) {
                if (wave < 8) asm volatile("s_waitcnt vmcnt(6)");
                else          asm volatile("s_waitcnt vmcnt(4)");
            } else if (t < 14) {
                if (wave < 8) asm volatile("s_waitcnt vmcnt(8)");
                else          asm volatile("s_waitcnt vmcnt(6)");
            } else if (t == 14) {
                if (wave < 8) asm volatile("s_waitcnt vmcnt(4)");
                else          asm volatile("s_waitcnt vmcnt(3)");
            } else {
                asm volatile("s_waitcnt vmcnt(0)");
            }
            __builtin_amdgcn_sched_barrier(0);
            __builtin_amdgcn_s_barrier();  // raw: all waves' stage(t) landed
            __builtin_amdgcn_sched_barrier(0);

            bf16x8 a[2];
            if (t < 8) {
#pragma unroll
                for (int kf = 0; kf < 2; ++kf)
                    a[kf] = *(const bf16x8*)((char*)xtL + arow * 1024 +
                                             ((t * 128 + kf * 64 + lg * 16) ^ sw));
            } else {
                a[0] = hc0;
                a[1] = hc1;
            }
            const char* bb = (const char*)Bst + (t % 3) * 24576;
            int rb0 = 16 * wu + l15;
            int swb = (rb0 & 7) << 4;
#pragma unroll
            for (int kf = 0; kf < 2; ++kf) {
                int kb = kf * 64 + lg * 16;
                bf16x8 br = *(const bf16x8*)(bb + (size_t)rb0 * 128 + (kb ^ swb));
                bf16x8 bz = *(const bf16x8*)(bb + (size_t)(64 + rb0) * 128 + (kb ^ swb));
                bf16x8 bn = *(const bf16x8*)(bb + (size_t)(128 + rb0) * 128 + (kb ^ swb));
                ar = __builtin_amdgcn_mfma_f32_16x16x32_bf16(a[kf], br, ar, 0, 0, 0);
                az = __builtin_amdgcn_mfma_f32_16x16x32_bf16(a[kf], bz, az, 0, 0, 0);
                if (t < 8)
                    agi = __builtin_amdgcn_mfma_f32_16x16x32_bf16(a[kf], bn, agi, 0, 0, 0);
                else
                    agh = __builtin_amdgcn_mfma_f32_16x16x32_bf16(a[kf], bn, agh, 0, 0, 0);
            }
            // rotate h-prefetch registers
            hc0 = hp1a;
            hc1 = hp1b;
            hp1a = hp2a;
            hp1b = hp2b;
            __builtin_amdgcn_sched_barrier(0);
            // end-of-iter raw barrier: next iter's stage targets (t+3)%3 =
            // t%3 only after ALL waves finished reading buf(t).
            __builtin_amdgcn_s_barrier();
        }
        // ---- GRU update epilogue ----
        int hu = S + 16 * wu + l15;
        float br_ = bih[hu] + bhh[hu];
        float bz_ = bih[512 + hu] + bhh[512 + hu];
        float bgi = bih[1024 + hu];
        float bgh = bhh[1024 + hu];
#pragma unroll
        for (int i = 0; i < 4; ++i) {
            int row = m0 + 16 * wr + lg * 4 + i;
            float rv = sigmoidf_(ar[i] + br_);
            float zv = sigmoidf_(az[i] + bz_);
            float nv = tanhf_(agi[i] + bgi + rv * (agh[i] + bgh));
            float hold = hfR[(size_t)row * 512 + hu];
            float hn = (1.f - zv) * nv + zv * hold;
            hfW[(size_t)row * 512 + hu] = hn;
            hbW[(size_t)row * 512 + hu] = f2bf(hn);
        }
    }
}

// ---------------------------------------------------------------------------
extern "C" void kernel_launch(void* const* d_in, const int* in_sizes, int n_in,
                              void* d_out, int out_size, void* d_ws,
                              size_t ws_size, hipStream_t stream) {
    (void)in_sizes; (void)n_in; (void)out_size;
    const float* x = (const float*)d_in[0];
    const float* eps = (const float*)d_in[2];
    const float* We1 = (const float*)d_in[3];
    const float* be1 = (const float*)d_in[4];
    const float* We2 = (const float*)d_in[5];
    const float* be2 = (const float*)d_in[6];
    const float* We3 = (const float*)d_in[7];
    const float* be3 = (const float*)d_in[8];
    const float* We41 = (const float*)d_in[9];
    const float* be41 = (const float*)d_in[10];
    const float* Wih = (const float*)d_in[11];
    const float* bih = (const float*)d_in[12];
    const float* Whh = (const float*)d_in[13];
    const float* bhh = (const float*)d_in[14];
    const float* Wf1 = (const float*)d_in[15];
    const float* bf1 = (const float*)d_in[16];
    const float* Wf2 = (const float*)d_in[17];
    const float* bf2 = (const float*)d_in[18];
    float* out = (float*)d_out;

    char* ws = (char*)d_ws;
    size_t off = 0;
    auto alloc = [&](size_t bytes) -> char* {
        char* p = ws + off;
        off += (bytes + 255) & ~(size_t)255;
        return p;
    };
    u16* xb = (u16*)alloc(2048ull * 4864 * 2);
    u16* We1b = (u16*)alloc(2048ull * 4864 * 2);
    u16* We2b = (u16*)alloc(1024ull * 2048 * 2);
    u16* We3b = (u16*)alloc(512ull * 1024 * 2);
    u16* We41b = (u16*)alloc(512ull * 512 * 2);
    u16* WB = (u16*)alloc(1536ull * 1024 * 2);
    u16* h1b = (u16*)alloc(2048ull * 2048 * 2);
    u16* h2b = (u16*)alloc(2048ull * 1024 * 2);
    u16* h3b = (u16*)alloc(2048ull * 512 * 2);
    u16* encb = (u16*)alloc(2048ull * 512 * 2);
    u16* hb0 = (u16*)alloc(2048ull * 512 * 2);
    u16* hb1 = (u16*)alloc(2048ull * 512 * 2);
    float* hf0 = (float*)alloc(2048ull * 512 * 4);
    float* hf1 = (float*)alloc(2048ull * 512 * 4);
    u16* Wf1p = (u16*)alloc(48ull * 512 * 2);
    u16* Wf2p = (u16*)alloc(512ull * 64 * 2);
    if (off > ws_size) {
        fill_const<<<(11010048 + 255) / 256, 256, 0, stream>>>(out, 11010048, 54321.0f);
        return;
    }
    u16* hb[2] = {hb0, hb1};
    float* hfl[2] = {hf0, hf1};

    // 1 setup launch + h init
    prep_all<<<8192, 256, 0, stream>>>(x, We1, We2, We3, We41, Wih, Whh, Wf1, Wf2,
                                       xb, We1b, We2b, We3b, We41b, WB, Wf1p, Wf2p);
    hipMemsetAsync(hb0, 0, 2048ull * 512 * 2, stream);
    hipMemsetAsync(hf0, 0, 2048ull * 512 * 4, stream);

    // encoder (bf16 MFMA), 4 launches
    gemm_bt<0><<<dim3(16, 16), 256, 0, stream>>>(xb, 4864, We1b, 4864, be1, h1b, 2048, 76, nullptr);
    gemm_bt<0><<<dim3(8, 16), 256, 0, stream>>>(h1b, 2048, We2b, 2048, be2, h2b, 1024, 32, nullptr);
    gemm_bt<0><<<dim3(4, 16), 256, 0, stream>>>(h2b, 1024, We3b, 1024, be3, h3b, 512, 16, nullptr);
    gemm_bt<1><<<dim3(4, 16), 256, 0, stream>>>(h3b, 512, We41b, 512, be41, encb, 512, 8, eps);

    // decoder: one fused kernel per step (2-deep pipelined gates)
    gru_step<0><<<256, 1024, 0, stream>>>(encb, hb0, hf0, hb1, hf1, WB, bih,
                                          bhh, Wf1p, bf1, Wf2p, bf2, out, 0);
    for (int i = 1; i < 128; ++i) {
        int p = i & 1;
        gru_step<1><<<256, 1024, 0, stream>>>(nullptr, hb[p], hfl[p],
                                              hb[p ^ 1], hfl[p ^ 1], WB, bih,
                                              bhh, Wf1p, bf1, Wf2p, bf2, out,
                                              i - 1);
    }
    gru_step<2><<<32, 1024, 0, stream>>>(nullptr, hb0, hf0, nullptr, nullptr,
                                         WB, bih, bhh, Wf1p, bf1, Wf2p, bf2,
                                         out, 127);
}